// Round 3
// baseline (38340.787 us; speedup 1.0000x reference)
//
#include <hip/hip_runtime.h>
#include <stdint.h>

// ---- types ----
typedef __attribute__((ext_vector_type(8))) short short8;   // 8 bf16 = 4 VGPR (MFMA A/B frag)
typedef __attribute__((ext_vector_type(4))) short short4v;  // 4 bf16 = 8B
typedef __attribute__((ext_vector_type(4))) float f32x4;    // MFMA C/D frag
typedef __attribute__((ext_vector_type(4))) unsigned int u32x4;

// ---- bf16 helpers (manual RNE) ----
__device__ inline unsigned short f2bf(float f) {
  unsigned int u = __builtin_bit_cast(unsigned int, f);
  u += 0x7fffu + ((u >> 16) & 1u);
  return (unsigned short)(u >> 16);
}
__device__ inline float bf2f(unsigned short s) {
  return __builtin_bit_cast(float, (unsigned int)s << 16);
}

// Problem constants: B=32, T=512, D=H=1024, 4H=4096, M = T*B = 16384
// gx layout: [t][n][b] bf16, n = permuted gate-row (4*j + gate), b = batch
// hs layout: [t][b][j]  bf16, flat row m = t*32+b (doubles as GEMM B-operand rows)

// ---- x: [B][T][D] f32  ->  xbf: [m = t*32+b][d] bf16 ----
__global__ __launch_bounds__(256) void cvt_x_kernel(const float* __restrict__ x,
                                                    short* __restrict__ xbf) {
  const int total = (16384 * 1024) / 4;
  for (int i = blockIdx.x * blockDim.x + threadIdx.x; i < total;
       i += gridDim.x * blockDim.x) {
    int d4 = i & 255;
    int m  = i >> 8;
    int t = m >> 5, b = m & 31;
    float4 v = *(const float4*)(x + ((size_t)b * 512 + t) * 1024 + (size_t)d4 * 4);
    short4v o;
    o.x = (short)f2bf(v.x); o.y = (short)f2bf(v.y);
    o.z = (short)f2bf(v.z); o.w = (short)f2bf(v.w);
    *(short4v*)(xbf + (size_t)m * 1024 + d4 * 4) = o;
  }
}

// ---- W: [4096][1024] f32 -> Wp: gate-interleaved rows, bf16.
// new row n = 4*j + g  <-  old row g*1024 + j ----
__global__ __launch_bounds__(256) void cvt_w_kernel(const float* __restrict__ W,
                                                    short* __restrict__ Wp) {
  const int total = (4096 * 1024) / 4;
  for (int i = blockIdx.x * blockDim.x + threadIdx.x; i < total;
       i += gridDim.x * blockDim.x) {
    int k4 = i & 255;
    int n  = i >> 8;
    int g = n & 3, j = n >> 2;
    float4 v = *(const float4*)(W + ((size_t)g * 1024 + j) * 1024 + (size_t)k4 * 4);
    short4v o;
    o.x = (short)f2bf(v.x); o.y = (short)f2bf(v.y);
    o.z = (short)f2bf(v.z); o.w = (short)f2bf(v.w);
    *(short4v*)(Wp + (size_t)n * 1024 + k4 * 4) = o;
  }
}

// ---- bias permute (stays f32) ----
__global__ __launch_bounds__(256) void cvt_b_kernel(const float* __restrict__ b,
                                                    float* __restrict__ bp) {
  int n = blockIdx.x * blockDim.x + threadIdx.x;
  if (n < 4096) bp[n] = b[(n & 3) * 1024 + (n >> 2)];
}

// ---- bf16 MFMA GEMM:  C[n][m] = sum_k A[n][k] * Bm[m][k]  (unchanged, proven) ----
__global__ __launch_bounds__(256) void gemm_bt(const short* __restrict__ A,
                                               const short* __restrict__ Bm,
                                               short* __restrict__ C) {
  const int n0 = blockIdx.x * 128;
  const int m0 = blockIdx.y * 128;
  const int tid = threadIdx.x;
  const int lane = tid & 63, wid = tid >> 6;
  const int wr = wid >> 1, wc = wid & 1;
  const int fr = lane & 15, fq = lane >> 4;

  __shared__ __align__(16) short As[128 * 32];
  __shared__ __align__(16) short Bs[128 * 32];

  f32x4 acc[4][4];
#pragma unroll
  for (int i = 0; i < 4; i++)
#pragma unroll
    for (int j = 0; j < 4; j++) acc[i][j] = (f32x4){0.f, 0.f, 0.f, 0.f};

  for (int kt = 0; kt < 1024; kt += 32) {
#pragma unroll
    for (int s = 0; s < 2; s++) {
      int c = tid + s * 256;
      int row = c >> 2;
      int off = (c & 3) * 8;
      *(u32x4*)&As[row * 32 + off] =
          *(const u32x4*)(A + (size_t)(n0 + row) * 1024 + kt + off);
      *(u32x4*)&Bs[row * 32 + off] =
          *(const u32x4*)(Bm + (size_t)(m0 + row) * 1024 + kt + off);
    }
    __syncthreads();
    short8 af[4], bf[4];
#pragma unroll
    for (int i = 0; i < 4; i++)
      af[i] = *(const short8*)&As[(wr * 64 + i * 16 + fr) * 32 + fq * 8];
#pragma unroll
    for (int j = 0; j < 4; j++)
      bf[j] = *(const short8*)&Bs[(wc * 64 + j * 16 + fr) * 32 + fq * 8];
#pragma unroll
    for (int i = 0; i < 4; i++)
#pragma unroll
      for (int j = 0; j < 4; j++)
        acc[i][j] = __builtin_amdgcn_mfma_f32_16x16x32_bf16(af[i], bf[j], acc[i][j], 0, 0, 0);
    __syncthreads();
  }

#pragma unroll
  for (int i = 0; i < 4; i++) {
#pragma unroll
    for (int j = 0; j < 4; j++) {
#pragma unroll
      for (int r = 0; r < 4; r++) {
        int n = n0 + wr * 64 + i * 16 + fq * 4 + r;
        int m = m0 + wc * 64 + j * 16 + fr;
        int t = m >> 5, b = m & 31;
        C[(size_t)t * 131072 + (size_t)n * 32 + b] = (short)f2bf(acc[i][j][r]);
      }
    }
  }
}

// ---- persistent LSTM layer: 64 WGs x 512 threads, 512 steps internally.
// WG owns 64 permuted gate-rows (16 h-cols). 8 waves = 4 row-tiles x 2 batch-halves.
// Lane (wn,wb,fq,fr) owns exactly one (b, j) for all steps -> c stays in a register.
// Device-wide sync: monotonic counter barrier (64 arrivals), release=threadfence+
// atomicAdd, acquire=__hip_atomic_load agent-scope spin. All 64 blocks trivially
// co-resident (512 thr, 0 LDS). ----
__global__ __launch_bounds__(512, 1) void lstm_layer(
    const short* __restrict__ gx, const short* __restrict__ Whh,
    const float* __restrict__ bias, short* __restrict__ hs,
    float* __restrict__ out, float* __restrict__ hn, float* __restrict__ cn,
    int* __restrict__ cnt) {
  const int wg = blockIdx.x;                 // 0..63
  const int tid = threadIdx.x;
  const int lane = tid & 63, w = tid >> 6;   // 8 waves
  const int wn = w >> 1, wb = w & 1;
  const int fr = lane & 15, fq = lane >> 4;
  const int n_base = wg * 64 + wn * 16;      // 16-row tile base (permuted gate rows)
  const int b = wb * 16 + fr;
  const int j = wg * 16 + wn * 4 + fq;       // h column this lane owns

  const short* arow = Whh + (size_t)(n_base + fr) * 1024 + fq * 8;
  float bia[4];
#pragma unroll
  for (int r = 0; r < 4; r++) bia[r] = bias[n_base + fq * 4 + r];

  float c = 0.f;
  for (int t = 0; t < 512; ++t) {
    f32x4 a0 = (f32x4){0,0,0,0}, a1 = (f32x4){0,0,0,0};
    f32x4 a2 = (f32x4){0,0,0,0}, a3 = (f32x4){0,0,0,0};
    if (t > 0) {
      const short* brow = hs + (size_t)(t - 1) * 32768 + (size_t)b * 1024 + fq * 8;
#pragma unroll
      for (int k = 0; k < 1024; k += 128) {
        short8 av0 = *(const short8*)(arow + k);
        short8 bv0 = *(const short8*)(brow + k);
        short8 av1 = *(const short8*)(arow + k + 32);
        short8 bv1 = *(const short8*)(brow + k + 32);
        short8 av2 = *(const short8*)(arow + k + 64);
        short8 bv2 = *(const short8*)(brow + k + 64);
        short8 av3 = *(const short8*)(arow + k + 96);
        short8 bv3 = *(const short8*)(brow + k + 96);
        a0 = __builtin_amdgcn_mfma_f32_16x16x32_bf16(av0, bv0, a0, 0, 0, 0);
        a1 = __builtin_amdgcn_mfma_f32_16x16x32_bf16(av1, bv1, a1, 0, 0, 0);
        a2 = __builtin_amdgcn_mfma_f32_16x16x32_bf16(av2, bv2, a2, 0, 0, 0);
        a3 = __builtin_amdgcn_mfma_f32_16x16x32_bf16(av3, bv3, a3, 0, 0, 0);
      }
    }
    const short* gxt = gx + (size_t)t * 131072;
    float pre[4];
#pragma unroll
    for (int r = 0; r < 4; r++) {
      int n = n_base + fq * 4 + r;
      pre[r] = (a0[r] + a1[r]) + (a2[r] + a3[r]) +
               bf2f((unsigned short)gxt[n * 32 + b]) + bia[r];
    }
    float iv = 1.f / (1.f + __expf(-pre[0]));
    float fv = 1.f / (1.f + __expf(-pre[1]));
    float gv = 2.f / (1.f + __expf(-2.f * pre[2])) - 1.f;
    float ov = 1.f / (1.f + __expf(-pre[3]));
    c = fv * c + iv * gv;
    float h = ov * (2.f / (1.f + __expf(-2.f * c)) - 1.f);

    hs[(size_t)t * 32768 + (size_t)b * 1024 + j] = (short)f2bf(h);
    if (out) out[(size_t)b * 524288 + (size_t)t * 1024 + j] = h;
    if (t == 511) {
      hn[b * 1024 + j] = h;
      cn[b * 1024 + j] = c;
      break;  // no barrier needed after last step
    }

    // ---- device-wide barrier ----
    __threadfence();          // release our h stores agent-wide
    __syncthreads();          // all block threads' stores+fences done
    if (tid == 0) {
      atomicAdd(cnt, 1);      // device-scope RMW
      const int target = 64 * (t + 1);
      while (__hip_atomic_load(cnt, __ATOMIC_ACQUIRE, __HIP_MEMORY_SCOPE_AGENT) < target)
        __builtin_amdgcn_s_sleep(8);
    }
    __syncthreads();
    __threadfence();          // acquire for all threads (invalidate stale L1)
  }
}

extern "C" void kernel_launch(void* const* d_in, const int* in_sizes, int n_in,
                              void* d_out, int out_size, void* d_ws, size_t ws_size,
                              hipStream_t stream) {
  const float* x    = (const float*)d_in[0];
  const float* Wih0 = (const float*)d_in[1];
  const float* b0   = (const float*)d_in[2];
  const float* Whh0 = (const float*)d_in[3];
  const float* Wih1 = (const float*)d_in[4];
  const float* b1   = (const float*)d_in[5];
  const float* Whh1 = (const float*)d_in[6];

  float* out = (float*)d_out;          // [32][512][1024]
  float* hn  = out + 16777216;         // [2][32][1024]
  float* cn  = hn + 65536;             // [2][32][1024]

  char* ws = (char*)d_ws;
  size_t off = 0;
  auto carve = [&](size_t bytes) {
    char* p = ws + off;
    off += (bytes + 255) & ~(size_t)255;
    return p;
  };
  short* xbf   = (short*)carve(16384ull * 1024 * 2);  // reused as hs1 later
  short* wih0p = (short*)carve(4096ull * 1024 * 2);
  short* whh0p = (short*)carve(4096ull * 1024 * 2);
  short* wih1p = (short*)carve(4096ull * 1024 * 2);
  short* whh1p = (short*)carve(4096ull * 1024 * 2);
  float* b0p   = (float*)carve(4096 * 4);
  float* b1p   = (float*)carve(4096 * 4);
  int*   cnt   = (int*)carve(256);                    // [0]=layer0, [1]=layer1
  short* gx    = (short*)carve(512ull * 4096 * 32 * 2);  // [t][n][b]
  short* hs0   = (short*)carve(16384ull * 1024 * 2);

  // barrier counters must start at 0 every call (ws is re-poisoned to 0xAA)
  hipMemsetAsync(cnt, 0, 8, stream);

  // phase 0: conversions / permutations
  hipLaunchKernelGGL(cvt_x_kernel, dim3(4096), dim3(256), 0, stream, x, xbf);
  hipLaunchKernelGGL(cvt_w_kernel, dim3(1024), dim3(256), 0, stream, Wih0, wih0p);
  hipLaunchKernelGGL(cvt_w_kernel, dim3(1024), dim3(256), 0, stream, Whh0, whh0p);
  hipLaunchKernelGGL(cvt_w_kernel, dim3(1024), dim3(256), 0, stream, Wih1, wih1p);
  hipLaunchKernelGGL(cvt_w_kernel, dim3(1024), dim3(256), 0, stream, Whh1, whh1p);
  hipLaunchKernelGGL(cvt_b_kernel, dim3(16), dim3(256), 0, stream, b0, b0p);
  hipLaunchKernelGGL(cvt_b_kernel, dim3(16), dim3(256), 0, stream, b1, b1p);

  // layer 0
  hipLaunchKernelGGL(gemm_bt, dim3(32, 128), dim3(256), 0, stream, wih0p, xbf, gx);
  hipLaunchKernelGGL(lstm_layer, dim3(64), dim3(512), 0, stream,
                     (const short*)gx, (const short*)whh0p, (const float*)b0p,
                     hs0, (float*)nullptr, hn, cn, cnt);

  // layer 1 (hs1 reuses xbf storage)
  hipLaunchKernelGGL(gemm_bt, dim3(32, 128), dim3(256), 0, stream, wih1p, hs0, gx);
  short* hs1 = xbf;
  hipLaunchKernelGGL(lstm_layer, dim3(64), dim3(512), 0, stream,
                     (const short*)gx, (const short*)whh1p, (const float*)b1p,
                     hs1, out, hn + 32768, cn + 32768, cnt + 1);
}

// Round 4
// 25005.180 us; speedup vs baseline: 1.5333x; 1.5333x over previous
//
#include <hip/hip_runtime.h>
#include <stdint.h>

// ---- types ----
typedef __attribute__((ext_vector_type(8))) short short8;   // 8 bf16 = 4 VGPR (MFMA A/B frag)
typedef __attribute__((ext_vector_type(4))) short short4v;  // 4 bf16 = 8B
typedef __attribute__((ext_vector_type(4))) float f32x4;    // MFMA C/D frag
typedef __attribute__((ext_vector_type(4))) unsigned int u32x4;
typedef __attribute__((ext_vector_type(2))) unsigned long long u64x2;

// ---- bf16 helpers (manual RNE) ----
__device__ inline unsigned short f2bf(float f) {
  unsigned int u = __builtin_bit_cast(unsigned int, f);
  u += 0x7fffu + ((u >> 16) & 1u);
  return (unsigned short)(u >> 16);
}
__device__ inline float bf2f(unsigned short s) {
  return __builtin_bit_cast(float, (unsigned int)s << 16);
}

// 16B coherent load built from two 8B agent-scope (sc1) loads: bypasses the
// non-coherent per-XCD L2s, reads the Infinity Cache coherence point.
__device__ inline short8 coh_load16(const short* p) {
  u64x2 t;
  t.x = __hip_atomic_load((const unsigned long long*)p,       __ATOMIC_RELAXED, __HIP_MEMORY_SCOPE_AGENT);
  t.y = __hip_atomic_load((const unsigned long long*)(p + 4), __ATOMIC_RELAXED, __HIP_MEMORY_SCOPE_AGENT);
  return __builtin_bit_cast(short8, t);
}

// Problem constants: B=32, T=512, D=H=1024, 4H=4096, M = T*B = 16384
// gx layout: [t][n][b] bf16, n = permuted gate-row (4*j + gate), b = batch
// hs layout: [t][b][j]  bf16, flat row m = t*32+b (doubles as GEMM B-operand rows)

// ---- x: [B][T][D] f32  ->  xbf: [m = t*32+b][d] bf16 ----
__global__ __launch_bounds__(256) void cvt_x_kernel(const float* __restrict__ x,
                                                    short* __restrict__ xbf) {
  const int total = (16384 * 1024) / 4;
  for (int i = blockIdx.x * blockDim.x + threadIdx.x; i < total;
       i += gridDim.x * blockDim.x) {
    int d4 = i & 255;
    int m  = i >> 8;
    int t = m >> 5, b = m & 31;
    float4 v = *(const float4*)(x + ((size_t)b * 512 + t) * 1024 + (size_t)d4 * 4);
    short4v o;
    o.x = (short)f2bf(v.x); o.y = (short)f2bf(v.y);
    o.z = (short)f2bf(v.z); o.w = (short)f2bf(v.w);
    *(short4v*)(xbf + (size_t)m * 1024 + d4 * 4) = o;
  }
}

// ---- W: [4096][1024] f32 -> Wp: gate-interleaved rows, bf16.
// new row n = 4*j + g  <-  old row g*1024 + j ----
__global__ __launch_bounds__(256) void cvt_w_kernel(const float* __restrict__ W,
                                                    short* __restrict__ Wp) {
  const int total = (4096 * 1024) / 4;
  for (int i = blockIdx.x * blockDim.x + threadIdx.x; i < total;
       i += gridDim.x * blockDim.x) {
    int k4 = i & 255;
    int n  = i >> 8;
    int g = n & 3, j = n >> 2;
    float4 v = *(const float4*)(W + ((size_t)g * 1024 + j) * 1024 + (size_t)k4 * 4);
    short4v o;
    o.x = (short)f2bf(v.x); o.y = (short)f2bf(v.y);
    o.z = (short)f2bf(v.z); o.w = (short)f2bf(v.w);
    *(short4v*)(Wp + (size_t)n * 1024 + k4 * 4) = o;
  }
}

// ---- bias permute (stays f32) ----
__global__ __launch_bounds__(256) void cvt_b_kernel(const float* __restrict__ b,
                                                    float* __restrict__ bp) {
  int n = blockIdx.x * blockDim.x + threadIdx.x;
  if (n < 4096) bp[n] = b[(n & 3) * 1024 + (n >> 2)];
}

// ---- bf16 MFMA GEMM:  C[n][m] = sum_k A[n][k] * Bm[m][k]  (unchanged, proven) ----
__global__ __launch_bounds__(256) void gemm_bt(const short* __restrict__ A,
                                               const short* __restrict__ Bm,
                                               short* __restrict__ C) {
  const int n0 = blockIdx.x * 128;
  const int m0 = blockIdx.y * 128;
  const int tid = threadIdx.x;
  const int lane = tid & 63, wid = tid >> 6;
  const int wr = wid >> 1, wc = wid & 1;
  const int fr = lane & 15, fq = lane >> 4;

  __shared__ __align__(16) short As[128 * 32];
  __shared__ __align__(16) short Bs[128 * 32];

  f32x4 acc[4][4];
#pragma unroll
  for (int i = 0; i < 4; i++)
#pragma unroll
    for (int j = 0; j < 4; j++) acc[i][j] = (f32x4){0.f, 0.f, 0.f, 0.f};

  for (int kt = 0; kt < 1024; kt += 32) {
#pragma unroll
    for (int s = 0; s < 2; s++) {
      int c = tid + s * 256;
      int row = c >> 2;
      int off = (c & 3) * 8;
      *(u32x4*)&As[row * 32 + off] =
          *(const u32x4*)(A + (size_t)(n0 + row) * 1024 + kt + off);
      *(u32x4*)&Bs[row * 32 + off] =
          *(const u32x4*)(Bm + (size_t)(m0 + row) * 1024 + kt + off);
    }
    __syncthreads();
    short8 af[4], bf[4];
#pragma unroll
    for (int i = 0; i < 4; i++)
      af[i] = *(const short8*)&As[(wr * 64 + i * 16 + fr) * 32 + fq * 8];
#pragma unroll
    for (int j = 0; j < 4; j++)
      bf[j] = *(const short8*)&Bs[(wc * 64 + j * 16 + fr) * 32 + fq * 8];
#pragma unroll
    for (int i = 0; i < 4; i++)
#pragma unroll
      for (int j = 0; j < 4; j++)
        acc[i][j] = __builtin_amdgcn_mfma_f32_16x16x32_bf16(af[i], bf[j], acc[i][j], 0, 0, 0);
    __syncthreads();
  }

#pragma unroll
  for (int i = 0; i < 4; i++) {
#pragma unroll
    for (int j = 0; j < 4; j++) {
#pragma unroll
      for (int r = 0; r < 4; r++) {
        int n = n0 + wr * 64 + i * 16 + fq * 4 + r;
        int m = m0 + wc * 64 + j * 16 + fr;
        int t = m >> 5, b = m & 31;
        C[(size_t)t * 131072 + (size_t)n * 32 + b] = (short)f2bf(acc[i][j][r]);
      }
    }
  }
}

// ---- persistent LSTM layer: 64 WGs x 512 threads, 512 steps internally.
// NO threadfence / cache-wide maintenance. h exchanged via agent-scope (sc1)
// 8B atomic stores/loads that hit the Infinity Cache coherence point directly.
// Barrier: 64 per-block monotonic flags; wave 0 polls all 64 in parallel lanes
// (one coalesced agent-scope load per round + __ballot). __syncthreads before
// the flag store drains vmcnt (compiler emits waitcnt before s_barrier), so
// all h stores have committed before the flag becomes visible. ----
__global__ __launch_bounds__(512, 1) void lstm_layer(
    const short* __restrict__ gx, const short* __restrict__ Whh,
    const float* __restrict__ bias, short* __restrict__ hs,
    float* __restrict__ out, float* __restrict__ hn, float* __restrict__ cn,
    int* __restrict__ flags) {
  const int wg = blockIdx.x;                 // 0..63
  const int tid = threadIdx.x;
  const int lane = tid & 63, w = tid >> 6;   // 8 waves
  const int wn = w >> 1, wb = w & 1;
  const int fr = lane & 15, fq = lane >> 4;
  const int n_base = wg * 64 + wn * 16;      // 16-row tile base (permuted gate rows)
  const int b = wb * 16 + fr;
  const int j = wg * 16 + wn * 4 + fq;       // h column this lane owns

  const short* arow = Whh + (size_t)(n_base + fr) * 1024 + fq * 8;
  float bia[4];
#pragma unroll
  for (int r = 0; r < 4; r++) bia[r] = bias[n_base + fq * 4 + r];

  float c = 0.f;
  for (int t = 0; t < 512; ++t) {
    f32x4 a0 = (f32x4){0,0,0,0}, a1 = (f32x4){0,0,0,0};
    f32x4 a2 = (f32x4){0,0,0,0}, a3 = (f32x4){0,0,0,0};
    if (t > 0) {
      const short* brow = hs + (size_t)(t - 1) * 32768 + (size_t)b * 1024 + fq * 8;
#pragma unroll
      for (int k = 0; k < 1024; k += 128) {
        short8 av0 = *(const short8*)(arow + k);
        short8 bv0 = coh_load16(brow + k);
        short8 av1 = *(const short8*)(arow + k + 32);
        short8 bv1 = coh_load16(brow + k + 32);
        short8 av2 = *(const short8*)(arow + k + 64);
        short8 bv2 = coh_load16(brow + k + 64);
        short8 av3 = *(const short8*)(arow + k + 96);
        short8 bv3 = coh_load16(brow + k + 96);
        a0 = __builtin_amdgcn_mfma_f32_16x16x32_bf16(av0, bv0, a0, 0, 0, 0);
        a1 = __builtin_amdgcn_mfma_f32_16x16x32_bf16(av1, bv1, a1, 0, 0, 0);
        a2 = __builtin_amdgcn_mfma_f32_16x16x32_bf16(av2, bv2, a2, 0, 0, 0);
        a3 = __builtin_amdgcn_mfma_f32_16x16x32_bf16(av3, bv3, a3, 0, 0, 0);
      }
    }
    const short* gxt = gx + (size_t)t * 131072;
    float pre[4];
#pragma unroll
    for (int r = 0; r < 4; r++) {
      int n = n_base + fq * 4 + r;
      pre[r] = (a0[r] + a1[r]) + (a2[r] + a3[r]) +
               bf2f((unsigned short)gxt[n * 32 + b]) + bia[r];
    }
    float iv = 1.f / (1.f + __expf(-pre[0]));
    float fv = 1.f / (1.f + __expf(-pre[1]));
    float gv = 2.f / (1.f + __expf(-2.f * pre[2])) - 1.f;
    float ov = 1.f / (1.f + __expf(-pre[3]));
    c = fv * c + iv * gv;
    float h = ov * (2.f / (1.f + __expf(-2.f * c)) - 1.f);

    // pack 4 gate-columns (lanes fq=0..3, same b,wn) into one 8B coherent store
    unsigned int hb = (unsigned int)f2bf(h);
    unsigned int v1 = __shfl(hb, fr + 16);
    unsigned int v2 = __shfl(hb, fr + 32);
    unsigned int v3 = __shfl(hb, fr + 48);
    if (fq == 0) {
      unsigned long long pk = (unsigned long long)hb |
                              ((unsigned long long)v1 << 16) |
                              ((unsigned long long)v2 << 32) |
                              ((unsigned long long)v3 << 48);
      __hip_atomic_store(
          (unsigned long long*)(hs + (size_t)t * 32768 + (size_t)b * 1024 + (wg * 16 + wn * 4)),
          pk, __ATOMIC_RELAXED, __HIP_MEMORY_SCOPE_AGENT);
    }
    if (out) out[(size_t)b * 524288 + (size_t)t * 1024 + j] = h;
    if (t == 511) {
      hn[b * 1024 + j] = h;
      cn[b * 1024 + j] = c;
      break;  // no barrier needed after last step
    }

    // ---- device-wide barrier, fence-free ----
    __syncthreads();  // every wave drains vmcnt before s_barrier -> h stores committed
    if (w == 0) {
      if (lane == 0)
        __hip_atomic_store(&flags[wg], t + 1, __ATOMIC_RELAXED, __HIP_MEMORY_SCOPE_AGENT);
      const int target = t + 1;
      unsigned long long pending;
      do {
        int v = __hip_atomic_load(&flags[lane], __ATOMIC_RELAXED, __HIP_MEMORY_SCOPE_AGENT);
        pending = __ballot(v < target);
      } while (pending);
    }
    __syncthreads();
  }
}

extern "C" void kernel_launch(void* const* d_in, const int* in_sizes, int n_in,
                              void* d_out, int out_size, void* d_ws, size_t ws_size,
                              hipStream_t stream) {
  const float* x    = (const float*)d_in[0];
  const float* Wih0 = (const float*)d_in[1];
  const float* b0   = (const float*)d_in[2];
  const float* Whh0 = (const float*)d_in[3];
  const float* Wih1 = (const float*)d_in[4];
  const float* b1   = (const float*)d_in[5];
  const float* Whh1 = (const float*)d_in[6];

  float* out = (float*)d_out;          // [32][512][1024]
  float* hn  = out + 16777216;         // [2][32][1024]
  float* cn  = hn + 65536;             // [2][32][1024]

  char* ws = (char*)d_ws;
  size_t off = 0;
  auto carve = [&](size_t bytes) {
    char* p = ws + off;
    off += (bytes + 255) & ~(size_t)255;
    return p;
  };
  short* xbf   = (short*)carve(16384ull * 1024 * 2);  // reused as hs1 later
  short* wih0p = (short*)carve(4096ull * 1024 * 2);
  short* whh0p = (short*)carve(4096ull * 1024 * 2);
  short* wih1p = (short*)carve(4096ull * 1024 * 2);
  short* whh1p = (short*)carve(4096ull * 1024 * 2);
  float* b0p   = (float*)carve(4096 * 4);
  float* b1p   = (float*)carve(4096 * 4);
  int*   flags = (int*)carve(512);                    // [0..63]=layer0, [64..127]=layer1
  short* gx    = (short*)carve(512ull * 4096 * 32 * 2);  // [t][n][b]
  short* hs0   = (short*)carve(16384ull * 1024 * 2);

  // flags must start at 0 every call (ws is re-poisoned to 0xAA)
  hipMemsetAsync(flags, 0, 512, stream);

  // phase 0: conversions / permutations
  hipLaunchKernelGGL(cvt_x_kernel, dim3(4096), dim3(256), 0, stream, x, xbf);
  hipLaunchKernelGGL(cvt_w_kernel, dim3(1024), dim3(256), 0, stream, Wih0, wih0p);
  hipLaunchKernelGGL(cvt_w_kernel, dim3(1024), dim3(256), 0, stream, Whh0, whh0p);
  hipLaunchKernelGGL(cvt_w_kernel, dim3(1024), dim3(256), 0, stream, Wih1, wih1p);
  hipLaunchKernelGGL(cvt_w_kernel, dim3(1024), dim3(256), 0, stream, Whh1, whh1p);
  hipLaunchKernelGGL(cvt_b_kernel, dim3(16), dim3(256), 0, stream, b0, b0p);
  hipLaunchKernelGGL(cvt_b_kernel, dim3(16), dim3(256), 0, stream, b1, b1p);

  // layer 0
  hipLaunchKernelGGL(gemm_bt, dim3(32, 128), dim3(256), 0, stream, wih0p, xbf, gx);
  hipLaunchKernelGGL(lstm_layer, dim3(64), dim3(512), 0, stream,
                     (const short*)gx, (const short*)whh0p, (const float*)b0p,
                     hs0, (float*)nullptr, hn, cn, flags);

  // layer 1 (hs1 reuses xbf storage)
  hipLaunchKernelGGL(gemm_bt, dim3(32, 128), dim3(256), 0, stream, wih1p, hs0, gx);
  short* hs1 = xbf;
  hipLaunchKernelGGL(lstm_layer, dim3(64), dim3(512), 0, stream,
                     (const short*)gx, (const short*)whh1p, (const float*)b1p,
                     hs1, out, hn + 32768, cn + 32768, flags + 64);
}

// Round 5
// 11723.303 us; speedup vs baseline: 3.2705x; 2.1329x over previous
//
#include <hip/hip_runtime.h>
#include <stdint.h>

// ---- types ----
typedef __attribute__((ext_vector_type(8))) short short8;   // 8 bf16 = 4 VGPR (MFMA A/B frag)
typedef __attribute__((ext_vector_type(4))) short short4v;  // 4 bf16 = 8B
typedef __attribute__((ext_vector_type(4))) float f32x4;    // MFMA C/D frag
typedef __attribute__((ext_vector_type(4))) unsigned int u32x4;
typedef __attribute__((ext_vector_type(4))) int i32x4;

// ---- bf16 helpers (manual RNE) ----
__device__ inline unsigned short f2bf(float f) {
  unsigned int u = __builtin_bit_cast(unsigned int, f);
  u += 0x7fffu + ((u >> 16) & 1u);
  return (unsigned short)(u >> 16);
}
__device__ inline float bf2f(unsigned short s) {
  return __builtin_bit_cast(float, (unsigned int)s << 16);
}

// Problem constants: B=32, T=512, D=H=1024, 4H=4096, M = T*B = 16384
// gx layout: [t][n][b] bf16, n = permuted gate-row (4*j + gate), b = batch
// hs layout: [t][b][j]  bf16, flat row m = t*32+b (doubles as GEMM B-operand rows)

// ---- x: [B][T][D] f32  ->  xbf: [m = t*32+b][d] bf16 ----
__global__ __launch_bounds__(256) void cvt_x_kernel(const float* __restrict__ x,
                                                    short* __restrict__ xbf) {
  const int total = (16384 * 1024) / 4;
  for (int i = blockIdx.x * blockDim.x + threadIdx.x; i < total;
       i += gridDim.x * blockDim.x) {
    int d4 = i & 255;
    int m  = i >> 8;
    int t = m >> 5, b = m & 31;
    float4 v = *(const float4*)(x + ((size_t)b * 512 + t) * 1024 + (size_t)d4 * 4);
    short4v o;
    o.x = (short)f2bf(v.x); o.y = (short)f2bf(v.y);
    o.z = (short)f2bf(v.z); o.w = (short)f2bf(v.w);
    *(short4v*)(xbf + (size_t)m * 1024 + d4 * 4) = o;
  }
}

// ---- W: [4096][1024] f32 -> Wp: gate-interleaved rows, bf16.
// new row n = 4*j + g  <-  old row g*1024 + j ----
__global__ __launch_bounds__(256) void cvt_w_kernel(const float* __restrict__ W,
                                                    short* __restrict__ Wp) {
  const int total = (4096 * 1024) / 4;
  for (int i = blockIdx.x * blockDim.x + threadIdx.x; i < total;
       i += gridDim.x * blockDim.x) {
    int k4 = i & 255;
    int n  = i >> 8;
    int g = n & 3, j = n >> 2;
    float4 v = *(const float4*)(W + ((size_t)g * 1024 + j) * 1024 + (size_t)k4 * 4);
    short4v o;
    o.x = (short)f2bf(v.x); o.y = (short)f2bf(v.y);
    o.z = (short)f2bf(v.z); o.w = (short)f2bf(v.w);
    *(short4v*)(Wp + (size_t)n * 1024 + k4 * 4) = o;
  }
}

// ---- bias permute (stays f32) ----
__global__ __launch_bounds__(256) void cvt_b_kernel(const float* __restrict__ b,
                                                    float* __restrict__ bp) {
  int n = blockIdx.x * blockDim.x + threadIdx.x;
  if (n < 4096) bp[n] = b[(n & 3) * 1024 + (n >> 2)];
}

// ---- bf16 MFMA GEMM:  C[n][m] = sum_k A[n][k] * Bm[m][k]  (unchanged, proven) ----
__global__ __launch_bounds__(256) void gemm_bt(const short* __restrict__ A,
                                               const short* __restrict__ Bm,
                                               short* __restrict__ C) {
  const int n0 = blockIdx.x * 128;
  const int m0 = blockIdx.y * 128;
  const int tid = threadIdx.x;
  const int lane = tid & 63, wid = tid >> 6;
  const int wr = wid >> 1, wc = wid & 1;
  const int fr = lane & 15, fq = lane >> 4;

  __shared__ __align__(16) short As[128 * 32];
  __shared__ __align__(16) short Bs[128 * 32];

  f32x4 acc[4][4];
#pragma unroll
  for (int i = 0; i < 4; i++)
#pragma unroll
    for (int j = 0; j < 4; j++) acc[i][j] = (f32x4){0.f, 0.f, 0.f, 0.f};

  for (int kt = 0; kt < 1024; kt += 32) {
#pragma unroll
    for (int s = 0; s < 2; s++) {
      int c = tid + s * 256;
      int row = c >> 2;
      int off = (c & 3) * 8;
      *(u32x4*)&As[row * 32 + off] =
          *(const u32x4*)(A + (size_t)(n0 + row) * 1024 + kt + off);
      *(u32x4*)&Bs[row * 32 + off] =
          *(const u32x4*)(Bm + (size_t)(m0 + row) * 1024 + kt + off);
    }
    __syncthreads();
    short8 af[4], bf[4];
#pragma unroll
    for (int i = 0; i < 4; i++)
      af[i] = *(const short8*)&As[(wr * 64 + i * 16 + fr) * 32 + fq * 8];
#pragma unroll
    for (int j = 0; j < 4; j++)
      bf[j] = *(const short8*)&Bs[(wc * 64 + j * 16 + fr) * 32 + fq * 8];
#pragma unroll
    for (int i = 0; i < 4; i++)
#pragma unroll
      for (int j = 0; j < 4; j++)
        acc[i][j] = __builtin_amdgcn_mfma_f32_16x16x32_bf16(af[i], bf[j], acc[i][j], 0, 0, 0);
    __syncthreads();
  }

#pragma unroll
  for (int i = 0; i < 4; i++) {
#pragma unroll
    for (int j = 0; j < 4; j++) {
#pragma unroll
      for (int r = 0; r < 4; r++) {
        int n = n0 + wr * 64 + i * 16 + fq * 4 + r;
        int m = m0 + wc * 64 + j * 16 + fr;
        int t = m >> 5, b = m & 31;
        C[(size_t)t * 131072 + (size_t)n * 32 + b] = (short)f2bf(acc[i][j][r]);
      }
    }
  }
}

// ---- persistent LSTM layer: 64 WGs x 512 threads, 512 steps internally.
// h[t-1] (64KB) is cooperatively staged into LDS each step via PIPELINED
// L2-bypassing loads (inline asm: 8x global_load_dwordx4 sc0 sc1 + one
// s_waitcnt) -> one latency window instead of 32 serialized atomic loads.
// LDS image is XOR-swizzled on 16B chunks (by b&7) so both ds_write_b128
// staging and ds_read_b128 B-fragment reads are <=2-way conflict (free).
// Producer h stores: packed 8B agent-scope atomic scatter (round-4 proven).
// Barrier: 64 per-block monotonic flags polled by wave 0's 64 lanes. ----
__global__ __launch_bounds__(512, 1) void lstm_layer(
    const short* __restrict__ gx, const short* __restrict__ Whh,
    const float* __restrict__ bias, short* __restrict__ hs,
    float* __restrict__ out, float* __restrict__ hn, float* __restrict__ cn,
    int* __restrict__ flags) {
  const int wg = blockIdx.x;                 // 0..63
  const int tid = threadIdx.x;
  const int lane = tid & 63, w = tid >> 6;   // 8 waves
  const int wn = w >> 1, wb = w & 1;
  const int fr = lane & 15, fq = lane >> 4;
  const int n_base = wg * 64 + wn * 16;      // 16-row tile base (permuted gate rows)
  const int b = wb * 16 + fr;
  const int j = wg * 16 + wn * 4 + fq;       // h column this lane owns
  const int sw = b & 7;                      // LDS chunk swizzle key

  __shared__ __align__(16) short hsh[32 * 1024];  // h[t-1] image, 64KB, swizzled

  const short* arow = Whh + (size_t)(n_base + fr) * 1024 + fq * 8;
  float bia[4];
#pragma unroll
  for (int r = 0; r < 4; r++) bia[r] = bias[n_base + fq * 4 + r];

  // staging addresses: thread handles 16B chunks c = tid + i*512 of the 64KB h
  unsigned int soff[8];
  int widx[8];
#pragma unroll
  for (int i = 0; i < 8; i++) {
    int c = tid + i * 512;
    soff[i] = (unsigned int)c * 16;          // byte offset into h[t-1]
    int bb = c >> 7, cc = c & 127;
    widx[i] = bb * 1024 + ((cc ^ (bb & 7)) << 3);  // swizzled LDS short-index
  }

  float c = 0.f;
  for (int t = 0; t < 512; ++t) {
    // gx loads hoisted: share the staging latency window
    const short* gxt = gx + (size_t)t * 131072;
    unsigned short g0 = (unsigned short)gxt[(n_base + fq * 4 + 0) * 32 + b];
    unsigned short g1 = (unsigned short)gxt[(n_base + fq * 4 + 1) * 32 + b];
    unsigned short g2 = (unsigned short)gxt[(n_base + fq * 4 + 2) * 32 + b];
    unsigned short g3 = (unsigned short)gxt[(n_base + fq * 4 + 3) * 32 + b];

    if (t > 0) {
      const short* hbase = hs + (size_t)(t - 1) * 32768;
      i32x4 r0, r1, r2, r3, r4, r5, r6, r7;
      asm volatile(
          "global_load_dwordx4 %0, %8, %16 sc0 sc1\n\t"
          "global_load_dwordx4 %1, %9, %16 sc0 sc1\n\t"
          "global_load_dwordx4 %2, %10, %16 sc0 sc1\n\t"
          "global_load_dwordx4 %3, %11, %16 sc0 sc1\n\t"
          "global_load_dwordx4 %4, %12, %16 sc0 sc1\n\t"
          "global_load_dwordx4 %5, %13, %16 sc0 sc1\n\t"
          "global_load_dwordx4 %6, %14, %16 sc0 sc1\n\t"
          "global_load_dwordx4 %7, %15, %16 sc0 sc1\n\t"
          "s_waitcnt vmcnt(0)"
          : "=&v"(r0), "=&v"(r1), "=&v"(r2), "=&v"(r3),
            "=&v"(r4), "=&v"(r5), "=&v"(r6), "=&v"(r7)
          : "v"(soff[0]), "v"(soff[1]), "v"(soff[2]), "v"(soff[3]),
            "v"(soff[4]), "v"(soff[5]), "v"(soff[6]), "v"(soff[7]),
            "s"(hbase)
          : "memory");
      *(i32x4*)&hsh[widx[0]] = r0;
      *(i32x4*)&hsh[widx[1]] = r1;
      *(i32x4*)&hsh[widx[2]] = r2;
      *(i32x4*)&hsh[widx[3]] = r3;
      *(i32x4*)&hsh[widx[4]] = r4;
      *(i32x4*)&hsh[widx[5]] = r5;
      *(i32x4*)&hsh[widx[6]] = r6;
      *(i32x4*)&hsh[widx[7]] = r7;
    }
    __syncthreads();  // LDS h-image ready (no-op work at t==0)

    f32x4 a0 = (f32x4){0,0,0,0}, a1 = (f32x4){0,0,0,0};
    f32x4 a2 = (f32x4){0,0,0,0}, a3 = (f32x4){0,0,0,0};
    if (t > 0) {
#pragma unroll
      for (int k = 0; k < 1024; k += 128) {
        const int chb = fq + (k >> 3);  // 16B chunk index base (compile-time part)
        short8 av0 = *(const short8*)(arow + k);
        short8 bv0 = *(const short8*)&hsh[b * 1024 + (((chb + 0) ^ sw) << 3)];
        short8 av1 = *(const short8*)(arow + k + 32);
        short8 bv1 = *(const short8*)&hsh[b * 1024 + (((chb + 4) ^ sw) << 3)];
        short8 av2 = *(const short8*)(arow + k + 64);
        short8 bv2 = *(const short8*)&hsh[b * 1024 + (((chb + 8) ^ sw) << 3)];
        short8 av3 = *(const short8*)(arow + k + 96);
        short8 bv3 = *(const short8*)&hsh[b * 1024 + (((chb + 12) ^ sw) << 3)];
        a0 = __builtin_amdgcn_mfma_f32_16x16x32_bf16(av0, bv0, a0, 0, 0, 0);
        a1 = __builtin_amdgcn_mfma_f32_16x16x32_bf16(av1, bv1, a1, 0, 0, 0);
        a2 = __builtin_amdgcn_mfma_f32_16x16x32_bf16(av2, bv2, a2, 0, 0, 0);
        a3 = __builtin_amdgcn_mfma_f32_16x16x32_bf16(av3, bv3, a3, 0, 0, 0);
      }
    }

    float pre[4];
    pre[0] = (a0[0] + a1[0]) + (a2[0] + a3[0]) + bf2f(g0) + bia[0];
    pre[1] = (a0[1] + a1[1]) + (a2[1] + a3[1]) + bf2f(g1) + bia[1];
    pre[2] = (a0[2] + a1[2]) + (a2[2] + a3[2]) + bf2f(g2) + bia[2];
    pre[3] = (a0[3] + a1[3]) + (a2[3] + a3[3]) + bf2f(g3) + bia[3];

    float iv = 1.f / (1.f + __expf(-pre[0]));
    float fv = 1.f / (1.f + __expf(-pre[1]));
    float gv = 2.f / (1.f + __expf(-2.f * pre[2])) - 1.f;
    float ov = 1.f / (1.f + __expf(-pre[3]));
    c = fv * c + iv * gv;
    float h = ov * (2.f / (1.f + __expf(-2.f * c)) - 1.f);

    // pack 4 gate-columns (lanes fq=0..3, same b,wn) into one 8B coherent store
    unsigned int hb = (unsigned int)f2bf(h);
    unsigned int v1 = __shfl(hb, fr + 16);
    unsigned int v2 = __shfl(hb, fr + 32);
    unsigned int v3 = __shfl(hb, fr + 48);
    if (fq == 0) {
      unsigned long long pk = (unsigned long long)hb |
                              ((unsigned long long)v1 << 16) |
                              ((unsigned long long)v2 << 32) |
                              ((unsigned long long)v3 << 48);
      __hip_atomic_store(
          (unsigned long long*)(hs + (size_t)t * 32768 + (size_t)b * 1024 + (wg * 16 + wn * 4)),
          pk, __ATOMIC_RELAXED, __HIP_MEMORY_SCOPE_AGENT);
    }
    if (out) out[(size_t)b * 524288 + (size_t)t * 1024 + j] = h;
    if (t == 511) {
      hn[b * 1024 + j] = h;
      cn[b * 1024 + j] = c;
      break;  // no barrier needed after last step
    }

    // ---- device-wide barrier, fence-free ----
    __syncthreads();  // drains vmcnt before s_barrier -> h stores committed; LDS reads done
    if (w == 0) {
      if (lane == 0)
        __hip_atomic_store(&flags[wg], t + 1, __ATOMIC_RELAXED, __HIP_MEMORY_SCOPE_AGENT);
      const int target = t + 1;
      unsigned long long pending;
      do {
        int v = __hip_atomic_load(&flags[lane], __ATOMIC_RELAXED, __HIP_MEMORY_SCOPE_AGENT);
        pending = __ballot(v < target);
      } while (pending);
    }
    __syncthreads();
  }
}

extern "C" void kernel_launch(void* const* d_in, const int* in_sizes, int n_in,
                              void* d_out, int out_size, void* d_ws, size_t ws_size,
                              hipStream_t stream) {
  const float* x    = (const float*)d_in[0];
  const float* Wih0 = (const float*)d_in[1];
  const float* b0   = (const float*)d_in[2];
  const float* Whh0 = (const float*)d_in[3];
  const float* Wih1 = (const float*)d_in[4];
  const float* b1   = (const float*)d_in[5];
  const float* Whh1 = (const float*)d_in[6];

  float* out = (float*)d_out;          // [32][512][1024]
  float* hn  = out + 16777216;         // [2][32][1024]
  float* cn  = hn + 65536;             // [2][32][1024]

  char* ws = (char*)d_ws;
  size_t off = 0;
  auto carve = [&](size_t bytes) {
    char* p = ws + off;
    off += (bytes + 255) & ~(size_t)255;
    return p;
  };
  short* xbf   = (short*)carve(16384ull * 1024 * 2);  // reused as hs1 later
  short* wih0p = (short*)carve(4096ull * 1024 * 2);
  short* whh0p = (short*)carve(4096ull * 1024 * 2);
  short* wih1p = (short*)carve(4096ull * 1024 * 2);
  short* whh1p = (short*)carve(4096ull * 1024 * 2);
  float* b0p   = (float*)carve(4096 * 4);
  float* b1p   = (float*)carve(4096 * 4);
  int*   flags = (int*)carve(512);                    // [0..63]=layer0, [64..127]=layer1
  short* gx    = (short*)carve(512ull * 4096 * 32 * 2);  // [t][n][b]
  short* hs0   = (short*)carve(16384ull * 1024 * 2);

  // flags must start at 0 every call (ws is re-poisoned to 0xAA)
  hipMemsetAsync(flags, 0, 512, stream);

  // phase 0: conversions / permutations
  hipLaunchKernelGGL(cvt_x_kernel, dim3(4096), dim3(256), 0, stream, x, xbf);
  hipLaunchKernelGGL(cvt_w_kernel, dim3(1024), dim3(256), 0, stream, Wih0, wih0p);
  hipLaunchKernelGGL(cvt_w_kernel, dim3(1024), dim3(256), 0, stream, Whh0, whh0p);
  hipLaunchKernelGGL(cvt_w_kernel, dim3(1024), dim3(256), 0, stream, Wih1, wih1p);
  hipLaunchKernelGGL(cvt_w_kernel, dim3(1024), dim3(256), 0, stream, Whh1, whh1p);
  hipLaunchKernelGGL(cvt_b_kernel, dim3(16), dim3(256), 0, stream, b0, b0p);
  hipLaunchKernelGGL(cvt_b_kernel, dim3(16), dim3(256), 0, stream, b1, b1p);

  // layer 0
  hipLaunchKernelGGL(gemm_bt, dim3(32, 128), dim3(256), 0, stream, wih0p, xbf, gx);
  hipLaunchKernelGGL(lstm_layer, dim3(64), dim3(512), 0, stream,
                     (const short*)gx, (const short*)whh0p, (const float*)b0p,
                     hs0, (float*)nullptr, hn, cn, flags);

  // layer 1 (hs1 reuses xbf storage; exchange-only, also feeds out directly)
  hipLaunchKernelGGL(gemm_bt, dim3(32, 128), dim3(256), 0, stream, wih1p, hs0, gx);
  short* hs1 = xbf;
  hipLaunchKernelGGL(lstm_layer, dim3(64), dim3(512), 0, stream,
                     (const short*)gx, (const short*)whh1p, (const float*)b1p,
                     hs1, out, hn + 32768, cn + 32768, flags + 64);
}

// Round 6
// 4328.446 us; speedup vs baseline: 8.8579x; 2.7084x over previous
//
#include <hip/hip_runtime.h>
#include <stdint.h>

// ---- types ----
typedef __attribute__((ext_vector_type(8))) short short8;   // 8 bf16 = 4 VGPR (MFMA A/B frag)
typedef __attribute__((ext_vector_type(4))) short short4v;  // 4 bf16 = 8B
typedef __attribute__((ext_vector_type(4))) float f32x4;    // MFMA C/D frag
typedef __attribute__((ext_vector_type(4))) unsigned int u32x4;
typedef __attribute__((ext_vector_type(4))) int i32x4;
typedef __attribute__((ext_vector_type(2))) unsigned long long u64x2;

// ---- bf16 helpers (manual RNE) ----
__device__ inline unsigned short f2bf(float f) {
  unsigned int u = __builtin_bit_cast(unsigned int, f);
  u += 0x7fffu + ((u >> 16) & 1u);
  return (unsigned short)(u >> 16);
}
__device__ inline float bf2f(unsigned short s) {
  return __builtin_bit_cast(float, (unsigned int)s << 16);
}

// sentinel = bf16 0x7F7F (=3.39e38). |h|<1 strictly -> high byte of any real h
// is never 0x7F, so sentinel cannot collide with produced data.
// stale64(v) != 0 iff any 16-bit lane of v equals 0x7F7F.
__device__ inline unsigned long long stale64(unsigned long long v) {
  unsigned long long x = v ^ 0x7f7f7f7f7f7f7f7full;
  return (x - 0x0001000100010001ull) & ~x & 0x8000800080008000ull;
}

// Problem constants: B=32, T=512, D=H=1024, 4H=4096, M = T*B = 16384
// gx layout: [t][b][n] bf16, n = permuted gate-row (4*j + gate)  (b-major!)
// hs layout: [t][b][j]  bf16, flat row m = t*32+b (doubles as GEMM B-operand rows)

// ---- x: [B][T][D] f32  ->  xbf: [m = t*32+b][d] bf16 ----
__global__ __launch_bounds__(256) void cvt_x_kernel(const float* __restrict__ x,
                                                    short* __restrict__ xbf) {
  const int total = (16384 * 1024) / 4;
  for (int i = blockIdx.x * blockDim.x + threadIdx.x; i < total;
       i += gridDim.x * blockDim.x) {
    int d4 = i & 255;
    int m  = i >> 8;
    int t = m >> 5, b = m & 31;
    float4 v = *(const float4*)(x + ((size_t)b * 512 + t) * 1024 + (size_t)d4 * 4);
    short4v o;
    o.x = (short)f2bf(v.x); o.y = (short)f2bf(v.y);
    o.z = (short)f2bf(v.z); o.w = (short)f2bf(v.w);
    *(short4v*)(xbf + (size_t)m * 1024 + d4 * 4) = o;
  }
}

// ---- W: [4096][1024] f32 -> Wp: gate-interleaved rows, bf16. ----
__global__ __launch_bounds__(256) void cvt_w_kernel(const float* __restrict__ W,
                                                    short* __restrict__ Wp) {
  const int total = (4096 * 1024) / 4;
  for (int i = blockIdx.x * blockDim.x + threadIdx.x; i < total;
       i += gridDim.x * blockDim.x) {
    int k4 = i & 255;
    int n  = i >> 8;
    int g = n & 3, j = n >> 2;
    float4 v = *(const float4*)(W + ((size_t)g * 1024 + j) * 1024 + (size_t)k4 * 4);
    short4v o;
    o.x = (short)f2bf(v.x); o.y = (short)f2bf(v.y);
    o.z = (short)f2bf(v.z); o.w = (short)f2bf(v.w);
    *(short4v*)(Wp + (size_t)n * 1024 + k4 * 4) = o;
  }
}

// ---- bias permute (stays f32) ----
__global__ __launch_bounds__(256) void cvt_b_kernel(const float* __restrict__ b,
                                                    float* __restrict__ bp) {
  int n = blockIdx.x * blockDim.x + threadIdx.x;
  if (n < 4096) bp[n] = b[(n & 3) * 1024 + (n >> 2)];
}

// ---- bf16 MFMA GEMM:  C[t][b][n] = sum_k A[n][k] * Bm[m=t*32+b][k]
// epilogue now packs 4 consecutive n (one lane's quad) into one 8B store. ----
__global__ __launch_bounds__(256) void gemm_bt(const short* __restrict__ A,
                                               const short* __restrict__ Bm,
                                               short* __restrict__ C) {
  const int n0 = blockIdx.x * 128;
  const int m0 = blockIdx.y * 128;
  const int tid = threadIdx.x;
  const int lane = tid & 63, wid = tid >> 6;
  const int wr = wid >> 1, wc = wid & 1;
  const int fr = lane & 15, fq = lane >> 4;

  __shared__ __align__(16) short As[128 * 32];
  __shared__ __align__(16) short Bs[128 * 32];

  f32x4 acc[4][4];
#pragma unroll
  for (int i = 0; i < 4; i++)
#pragma unroll
    for (int j = 0; j < 4; j++) acc[i][j] = (f32x4){0.f, 0.f, 0.f, 0.f};

  for (int kt = 0; kt < 1024; kt += 32) {
#pragma unroll
    for (int s = 0; s < 2; s++) {
      int c = tid + s * 256;
      int row = c >> 2;
      int off = (c & 3) * 8;
      *(u32x4*)&As[row * 32 + off] =
          *(const u32x4*)(A + (size_t)(n0 + row) * 1024 + kt + off);
      *(u32x4*)&Bs[row * 32 + off] =
          *(const u32x4*)(Bm + (size_t)(m0 + row) * 1024 + kt + off);
    }
    __syncthreads();
    short8 af[4], bf[4];
#pragma unroll
    for (int i = 0; i < 4; i++)
      af[i] = *(const short8*)&As[(wr * 64 + i * 16 + fr) * 32 + fq * 8];
#pragma unroll
    for (int j = 0; j < 4; j++)
      bf[j] = *(const short8*)&Bs[(wc * 64 + j * 16 + fr) * 32 + fq * 8];
#pragma unroll
    for (int i = 0; i < 4; i++)
#pragma unroll
      for (int j = 0; j < 4; j++)
        acc[i][j] = __builtin_amdgcn_mfma_f32_16x16x32_bf16(af[i], bf[j], acc[i][j], 0, 0, 0);
    __syncthreads();
  }

#pragma unroll
  for (int i = 0; i < 4; i++) {
#pragma unroll
    for (int j = 0; j < 4; j++) {
      int nq = n0 + wr * 64 + i * 16 + fq * 4;      // quad-aligned n base
      int m = m0 + wc * 64 + j * 16 + fr;
      int t = m >> 5, b = m & 31;
      unsigned long long pk = 0;
#pragma unroll
      for (int r = 0; r < 4; r++)
        pk |= (unsigned long long)f2bf(acc[i][j][r]) << (16 * r);
      *(unsigned long long*)&C[(size_t)t * 131072 + (size_t)b * 4096 + nq] = pk;
    }
  }
}

// ---- persistent LSTM layer: 64 WGs x 512 threads, 512 steps, NO barrier.
// hs is pre-filled with sentinel 0x7F7F; the packed 8B agent-scope h store IS
// the readiness signal. Each step, each thread poll-stages its 8 16B chunks of
// h[t-1] with L2-bypassing loads (sc0 sc1) until sentinel-free, writes them to
// a swizzled LDS image; k-loop is pure ds_read_b128 + MFMA with the lane's
// 512B Whh slice preloaded into registers (1 WG/CU -> VGPRs are free). ----
__global__ __launch_bounds__(512, 1) void lstm_layer(
    const short* __restrict__ gx, const short* __restrict__ Whh,
    const float* __restrict__ bias, short* __restrict__ hs,
    float* __restrict__ out, float* __restrict__ hn, float* __restrict__ cn) {
  const int wg = blockIdx.x;                 // 0..63
  const int tid = threadIdx.x;
  const int lane = tid & 63, w = tid >> 6;   // 8 waves
  const int wn = w >> 1, wb = w & 1;
  const int fr = lane & 15, fq = lane >> 4;
  const int n_base = wg * 64 + wn * 16;      // 16-row tile base (permuted gate rows)
  const int b = wb * 16 + fr;
  const int j = wg * 16 + wn * 4 + fq;       // h column this lane owns
  const int sw = b & 7;                      // LDS chunk swizzle key

  __shared__ __align__(16) short hsh[32 * 1024];  // h[t-1] image, 64KB, swizzled

  // preload this lane's Whh slice into registers: 32 x 16B = 512B = 128 VGPRs
  const short* arow = Whh + (size_t)(n_base + fr) * 1024 + fq * 8;
  short8 wreg[32];
#pragma unroll
  for (int kk = 0; kk < 32; kk++) wreg[kk] = *(const short8*)(arow + kk * 32);

  float bia[4];
#pragma unroll
  for (int r = 0; r < 4; r++) bia[r] = bias[n_base + fq * 4 + r];

  // staging addresses: thread handles 16B chunks c = tid + i*512 of the 64KB h
  unsigned int soff[8];
  int widx[8];
#pragma unroll
  for (int i = 0; i < 8; i++) {
    int c = tid + i * 512;
    soff[i] = (unsigned int)c * 16;          // byte offset into h[t-1]
    int bb = c >> 7, cc = c & 127;
    widx[i] = bb * 1024 + ((cc ^ (bb & 7)) << 3);  // swizzled LDS short-index
  }

  float c = 0.f;
  for (int t = 0; t < 512; ++t) {
    // gx: one 8B cached load gives the 4 gate pre-activations for (b, j)
    unsigned long long gq = *(const unsigned long long*)(
        gx + (size_t)t * 131072 + (size_t)b * 4096 + n_base + fq * 4);

    if (t > 0) {
      const short* hbase = hs + (size_t)(t - 1) * 32768;
      i32x4 r0, r1, r2, r3, r4, r5, r6, r7;
      // poll until all 8 chunks are sentinel-free (producer store = signal)
      while (true) {
        asm volatile(
            "global_load_dwordx4 %0, %8, %16 sc0 sc1\n\t"
            "global_load_dwordx4 %1, %9, %16 sc0 sc1\n\t"
            "global_load_dwordx4 %2, %10, %16 sc0 sc1\n\t"
            "global_load_dwordx4 %3, %11, %16 sc0 sc1\n\t"
            "global_load_dwordx4 %4, %12, %16 sc0 sc1\n\t"
            "global_load_dwordx4 %5, %13, %16 sc0 sc1\n\t"
            "global_load_dwordx4 %6, %14, %16 sc0 sc1\n\t"
            "global_load_dwordx4 %7, %15, %16 sc0 sc1\n\t"
            "s_waitcnt vmcnt(0)"
            : "=&v"(r0), "=&v"(r1), "=&v"(r2), "=&v"(r3),
              "=&v"(r4), "=&v"(r5), "=&v"(r6), "=&v"(r7)
            : "v"(soff[0]), "v"(soff[1]), "v"(soff[2]), "v"(soff[3]),
              "v"(soff[4]), "v"(soff[5]), "v"(soff[6]), "v"(soff[7]),
              "s"(hbase)
            : "memory");
        u64x2 q0 = __builtin_bit_cast(u64x2, r0), q1 = __builtin_bit_cast(u64x2, r1);
        u64x2 q2 = __builtin_bit_cast(u64x2, r2), q3 = __builtin_bit_cast(u64x2, r3);
        u64x2 q4 = __builtin_bit_cast(u64x2, r4), q5 = __builtin_bit_cast(u64x2, r5);
        u64x2 q6 = __builtin_bit_cast(u64x2, r6), q7 = __builtin_bit_cast(u64x2, r7);
        unsigned long long bad =
            stale64(q0.x) | stale64(q0.y) | stale64(q1.x) | stale64(q1.y) |
            stale64(q2.x) | stale64(q2.y) | stale64(q3.x) | stale64(q3.y) |
            stale64(q4.x) | stale64(q4.y) | stale64(q5.x) | stale64(q5.y) |
            stale64(q6.x) | stale64(q6.y) | stale64(q7.x) | stale64(q7.y);
        if (!bad) break;
      }
      *(i32x4*)&hsh[widx[0]] = r0;
      *(i32x4*)&hsh[widx[1]] = r1;
      *(i32x4*)&hsh[widx[2]] = r2;
      *(i32x4*)&hsh[widx[3]] = r3;
      *(i32x4*)&hsh[widx[4]] = r4;
      *(i32x4*)&hsh[widx[5]] = r5;
      *(i32x4*)&hsh[widx[6]] = r6;
      *(i32x4*)&hsh[widx[7]] = r7;
    }
    __syncthreads();  // LDS h-image ready

    f32x4 a0 = (f32x4){0,0,0,0}, a1 = (f32x4){0,0,0,0};
    f32x4 a2 = (f32x4){0,0,0,0}, a3 = (f32x4){0,0,0,0};
    if (t > 0) {
#pragma unroll
      for (int m = 0; m < 8; m++) {
        const int chb = fq + m * 16;  // 16B chunk index base within b-row
        short8 bv0 = *(const short8*)&hsh[b * 1024 + (((chb + 0) ^ sw) << 3)];
        short8 bv1 = *(const short8*)&hsh[b * 1024 + (((chb + 4) ^ sw) << 3)];
        short8 bv2 = *(const short8*)&hsh[b * 1024 + (((chb + 8) ^ sw) << 3)];
        short8 bv3 = *(const short8*)&hsh[b * 1024 + (((chb + 12) ^ sw) << 3)];
        a0 = __builtin_amdgcn_mfma_f32_16x16x32_bf16(wreg[4 * m + 0], bv0, a0, 0, 0, 0);
        a1 = __builtin_amdgcn_mfma_f32_16x16x32_bf16(wreg[4 * m + 1], bv1, a1, 0, 0, 0);
        a2 = __builtin_amdgcn_mfma_f32_16x16x32_bf16(wreg[4 * m + 2], bv2, a2, 0, 0, 0);
        a3 = __builtin_amdgcn_mfma_f32_16x16x32_bf16(wreg[4 * m + 3], bv3, a3, 0, 0, 0);
      }
    }

    float pre[4];
    pre[0] = (a0[0] + a1[0]) + (a2[0] + a3[0]) + bf2f((unsigned short)(gq       & 0xFFFF)) + bia[0];
    pre[1] = (a0[1] + a1[1]) + (a2[1] + a3[1]) + bf2f((unsigned short)((gq >> 16) & 0xFFFF)) + bia[1];
    pre[2] = (a0[2] + a1[2]) + (a2[2] + a3[2]) + bf2f((unsigned short)((gq >> 32) & 0xFFFF)) + bia[2];
    pre[3] = (a0[3] + a1[3]) + (a2[3] + a3[3]) + bf2f((unsigned short)((gq >> 48) & 0xFFFF)) + bia[3];

    float iv = 1.f / (1.f + __expf(-pre[0]));
    float fv = 1.f / (1.f + __expf(-pre[1]));
    float gv = 2.f / (1.f + __expf(-2.f * pre[2])) - 1.f;
    float ov = 1.f / (1.f + __expf(-pre[3]));
    c = fv * c + iv * gv;
    float h = ov * (2.f / (1.f + __expf(-2.f * c)) - 1.f);

    // pack 4 gate-columns (lanes fq=0..3, same b,wn) into one 8B coherent store
    unsigned int hb = (unsigned int)f2bf(h);
    unsigned int v1 = __shfl(hb, fr + 16);
    unsigned int v2 = __shfl(hb, fr + 32);
    unsigned int v3 = __shfl(hb, fr + 48);
    if (fq == 0) {
      unsigned long long pk = (unsigned long long)hb |
                              ((unsigned long long)v1 << 16) |
                              ((unsigned long long)v2 << 32) |
                              ((unsigned long long)v3 << 48);
      __hip_atomic_store(
          (unsigned long long*)(hs + (size_t)t * 32768 + (size_t)b * 1024 + (wg * 16 + wn * 4)),
          pk, __ATOMIC_RELAXED, __HIP_MEMORY_SCOPE_AGENT);
    }
    if (out) out[(size_t)b * 524288 + (size_t)t * 1024 + j] = h;
    if (t == 511) {
      hn[b * 1024 + j] = h;
      cn[b * 1024 + j] = c;
      break;
    }
    __syncthreads();  // protect LDS image until all waves' k-loop reads done
  }
}

extern "C" void kernel_launch(void* const* d_in, const int* in_sizes, int n_in,
                              void* d_out, int out_size, void* d_ws, size_t ws_size,
                              hipStream_t stream) {
  const float* x    = (const float*)d_in[0];
  const float* Wih0 = (const float*)d_in[1];
  const float* b0   = (const float*)d_in[2];
  const float* Whh0 = (const float*)d_in[3];
  const float* Wih1 = (const float*)d_in[4];
  const float* b1   = (const float*)d_in[5];
  const float* Whh1 = (const float*)d_in[6];

  float* out = (float*)d_out;          // [32][512][1024]
  float* hn  = out + 16777216;         // [2][32][1024]
  float* cn  = hn + 65536;             // [2][32][1024]

  char* ws = (char*)d_ws;
  size_t off = 0;
  auto carve = [&](size_t bytes) {
    char* p = ws + off;
    off += (bytes + 255) & ~(size_t)255;
    return p;
  };
  short* xbf   = (short*)carve(16384ull * 1024 * 2);  // reused as hs1 later
  short* wih0p = (short*)carve(4096ull * 1024 * 2);
  short* whh0p = (short*)carve(4096ull * 1024 * 2);
  short* wih1p = (short*)carve(4096ull * 1024 * 2);
  short* whh1p = (short*)carve(4096ull * 1024 * 2);
  float* b0p   = (float*)carve(4096 * 4);
  float* b1p   = (float*)carve(4096 * 4);
  short* gx    = (short*)carve(512ull * 4096 * 32 * 2);  // [t][b][n]
  short* hs0   = (short*)carve(16384ull * 1024 * 2);

  // phase 0: conversions / permutations
  hipLaunchKernelGGL(cvt_x_kernel, dim3(4096), dim3(256), 0, stream, x, xbf);
  hipLaunchKernelGGL(cvt_w_kernel, dim3(1024), dim3(256), 0, stream, Wih0, wih0p);
  hipLaunchKernelGGL(cvt_w_kernel, dim3(1024), dim3(256), 0, stream, Whh0, whh0p);
  hipLaunchKernelGGL(cvt_w_kernel, dim3(1024), dim3(256), 0, stream, Wih1, wih1p);
  hipLaunchKernelGGL(cvt_w_kernel, dim3(1024), dim3(256), 0, stream, Whh1, whh1p);
  hipLaunchKernelGGL(cvt_b_kernel, dim3(16), dim3(256), 0, stream, b0, b0p);
  hipLaunchKernelGGL(cvt_b_kernel, dim3(16), dim3(256), 0, stream, b1, b1p);
  // sentinel-fill hs0 (bf16 0x7F7F) before layer-0 recurrence
  hipMemsetAsync(hs0, 0x7F, 16384ull * 1024 * 2, stream);

  // layer 0
  hipLaunchKernelGGL(gemm_bt, dim3(32, 128), dim3(256), 0, stream, wih0p, xbf, gx);
  hipLaunchKernelGGL(lstm_layer, dim3(64), dim3(512), 0, stream,
                     (const short*)gx, (const short*)whh0p, (const float*)b0p,
                     hs0, (float*)nullptr, hn, cn);

  // layer 1: xbf is dead after gemm0 -> sentinel-fill and reuse as hs1
  short* hs1 = xbf;
  hipMemsetAsync(hs1, 0x7F, 16384ull * 1024 * 2, stream);
  hipLaunchKernelGGL(gemm_bt, dim3(32, 128), dim3(256), 0, stream, wih1p, hs0, gx);
  hipLaunchKernelGGL(lstm_layer, dim3(64), dim3(512), 0, stream,
                     (const short*)gx, (const short*)whh1p, (const float*)b1p,
                     hs1, out, hn + 32768, cn + 32768);
}